// Round 3
// baseline (84.024 us; speedup 1.0000x reference)
//
#include <hip/hip_runtime.h>

#define BATCH 8
#define CH 64
#define CIN 3
#define HIN 224
#define WIN 224
#define KSZ 5
#define STRIDE 2
#define HO 110
#define WO 110
#define RY 10
#define RX 2
#define GROUPS (HO / RY)                    // 11
#define PAIRS (WO / RX)                     // 55
#define ITEMS (GROUPS * PAIRS)              // 605 per plane
#define TPB 128
#define BLOCKS_X ((ITEMS + TPB - 1) / TPB)  // 5
#define NPLANES (BATCH * CH)                // 512
#define NWG (BLOCKS_X * NPLANES)            // 2560 (div by 8 -> bijective swizzle)
#define NROWS (STRIDE * (RY - 1) + KSZ)     // 23 input rows per thread
#define RWIDTH (STRIDE * (RX - 1) + KSZ)    // 7 input floats per row

typedef float float4a __attribute__((ext_vector_type(4)));  // 16B aligned
typedef float float2a __attribute__((ext_vector_type(2)));  // 8B aligned

__global__ __launch_bounds__(TPB) void conv5_reg2_kernel(
    const float* __restrict__ x,
    const float* __restrict__ Wt,
    float* __restrict__ out)
{
    __shared__ float wsh[CIN * KSZ * KSZ];  // 75 floats

    // flatten + bijective XCD swizzle: all 5 x-blocks of a plane -> same XCD
    const int wg = blockIdx.x;
    const int per = NWG >> 3;                // 320
    const int swz = (wg & 7) * per + (wg >> 3);
    const int bc   = swz / BLOCKS_X;
    const int xblk = swz - bc * BLOCKS_X;
    const int c = bc & (CH - 1);

    const int tid = threadIdx.x;
    if (tid < CIN * KSZ * KSZ) {
        wsh[tid] = Wt[c * (CIN * KSZ * KSZ) + tid];
    }
    __syncthreads();

    const int idx = xblk * TPB + tid;
    if (idx >= ITEMS) return;

    const int px = idx % PAIRS;              // horizontal pair index (fast dim)
    const int g  = idx / PAIRS;              // vertical group
    const int ho0 = g * RY;
    const int ih0 = ho0 * STRIDE;
    const int iw0 = px * (RX * STRIDE);      // 4*px -> 16B aligned

    float acc[RY][RX];
#pragma unroll
    for (int t = 0; t < RY; ++t)
#pragma unroll
        for (int u = 0; u < RX; ++u) acc[t][u] = 0.f;

    const float* xb = x + (size_t)bc * (CIN * HIN * WIN);

#pragma unroll
    for (int ci = 0; ci < CIN; ++ci) {
        float wr[KSZ * KSZ];
#pragma unroll
        for (int i = 0; i < KSZ * KSZ; ++i) wr[i] = wsh[ci * KSZ * KSZ + i];

        const float* xp = xb + (size_t)ci * HIN * WIN + (size_t)ih0 * WIN + iw0;
#pragma unroll
        for (int r = 0; r < NROWS; ++r) {    // 23 rows feed 10 vertical outputs
            const float* rp = xp + r * WIN;
            float4a v0 = *reinterpret_cast<const float4a*>(rp);      // iw0..+3 (16B aligned)
            float4a v1 = *reinterpret_cast<const float4a*>(rp + 4);  // iw0+4..+7 (in-bounds: iw0+7<=223)
            float xv[8] = {v0.x, v0.y, v0.z, v0.w, v1.x, v1.y, v1.z, v1.w};
#pragma unroll
            for (int t = 0; t < RY; ++t) {
                const int kh = r - STRIDE * t;
                if (kh >= 0 && kh < KSZ) {
#pragma unroll
                    for (int kw = 0; kw < KSZ; ++kw) {
                        const float w = wr[kh * KSZ + kw];
                        acc[t][0] = fmaf(xv[kw],     w, acc[t][0]);
                        acc[t][1] = fmaf(xv[kw + 2], w, acc[t][1]);
                    }
                }
            }
        }
    }

    float* op = out + (size_t)bc * (HO * WO) + (size_t)ho0 * WO + px * RX;
#pragma unroll
    for (int t = 0; t < RY; ++t) {
        float2a v = {acc[t][0], acc[t][1]};
        *reinterpret_cast<float2a*>(op + (size_t)t * WO) = v;
    }
}

extern "C" void kernel_launch(void* const* d_in, const int* in_sizes, int n_in,
                              void* d_out, int out_size, void* d_ws, size_t ws_size,
                              hipStream_t stream)
{
    const float* x  = (const float*)d_in[0];
    const float* Wt = (const float*)d_in[1];
    float* out = (float*)d_out;

    conv5_reg2_kernel<<<dim3(NWG), dim3(TPB), 0, stream>>>(x, Wt, out);
}

// Round 4
// 74.237 us; speedup vs baseline: 1.1318x; 1.1318x over previous
//
#include <hip/hip_runtime.h>

#define BATCH 8
#define CH 64
#define CIN 3
#define HIN 224
#define WIN 224
#define KSZ 5
#define STRIDE 2
#define HO 110
#define WO 110

#define TROWS 10                          // output rows per block tile
#define TILES (HO / TROWS)                // 11
#define NPLANES (BATCH * CH)              // 512
#define NWG (NPLANES * TILES)             // 5632 = 8 * 704 -> bijective XCD swizzle
#define INROWS (STRIDE * (TROWS - 1) + KSZ) // 23 input rows per tile
#define SLABF (INROWS * WIN)              // 5152 floats per ci slab
#define SLABU (SLABF / 4)                 // 1288 16B units per slab
#define TOTU (CIN * SLABU)                // 3864 16B units per tile
#define TPB 128
#define NITER ((TOTU + TPB - 1) / TPB)    // 31 (30 full + 24-lane remainder)

typedef float float4a __attribute__((ext_vector_type(4)));
typedef float float2a __attribute__((ext_vector_type(2)));

#define GLOAD_LDS16(gsrc, ldsdst) \
    __builtin_amdgcn_global_load_lds((const __attribute__((address_space(1))) void*)(gsrc), \
                                     (__attribute__((address_space(3))) void*)(ldsdst), 16, 0, 0)

__global__ __launch_bounds__(TPB) void conv5_lds_kernel(
    const float* __restrict__ x,
    const float* __restrict__ Wt,
    float* __restrict__ out)
{
    __shared__ float xs[CIN * SLABF];        // 61,824 B, linear copy of the 3 slabs
    __shared__ float wsh[CIN * KSZ * KSZ];   // 300 B

    // bijective XCD swizzle: all 11 tiles of a plane stay in one XCD chunk
    const int wg  = blockIdx.x;
    const int per = NWG >> 3;                // 704
    const int swz = (wg & 7) * per + (wg >> 3);
    const int bc   = swz / TILES;
    const int tile = swz - bc * TILES;
    const int c = bc & (CH - 1);
    const int ho0 = tile * TROWS;
    const int ih0 = ho0 * STRIDE;            // <= 200, +22 <= 222 in-bounds

    const int tid = threadIdx.x;
    if (tid < CIN * KSZ * KSZ) {
        wsh[tid] = Wt[c * (CIN * KSZ * KSZ) + tid];
    }

    // ---- stage: global -> LDS via async DMA, 16B/lane, linear both sides ----
    const char* gbase = (const char*)(x + (size_t)bc * (CIN * HIN * WIN));
#pragma unroll
    for (int k = 0; k < NITER; ++k) {
        const int u = k * TPB + tid;                 // 16B unit index in tile
        const int ci = (u >= 2 * SLABU) ? 2 : (u >= SLABU ? 1 : 0);
        const int rem = u - ci * SLABU;              // unit within slab
        const char* src = gbase + (size_t)ci * (HIN * WIN * 4)
                                + (size_t)ih0 * (WIN * 4)
                                + (size_t)rem * 16;
        // wave-uniform LDS base (lane offset x16 added by HW)
        char* dst = (char*)xs + (size_t)(k * TPB + (tid & ~63)) * 16;
        if (u < TOTU) {
            GLOAD_LDS16(src, dst);
        }
    }

    __syncthreads();   // compiler drains vmcnt (incl. LDS-DMA) before s_barrier

    // ---- compute: 110 active threads, each 5 rows x 2 cols ----
    if (tid >= 110) return;                  // no further barriers
    const int px = tid % 55;                 // horizontal pair (cols 2px, 2px+1)
    const int ty = tid / 55;                 // vertical half (rows ho0+5ty..+4)
    const int r0 = 10 * ty;                  // first tile-local input row

    float acc[5][2];
#pragma unroll
    for (int t = 0; t < 5; ++t) { acc[t][0] = 0.f; acc[t][1] = 0.f; }

#pragma unroll
    for (int ci = 0; ci < CIN; ++ci) {
        float wr[KSZ * KSZ];
#pragma unroll
        for (int i = 0; i < KSZ * KSZ; ++i) wr[i] = wsh[ci * KSZ * KSZ + i];

        const float* sp = xs + ci * SLABF + r0 * WIN + 4 * px;  // 16B aligned
#pragma unroll
        for (int rr = 0; rr < 13; ++rr) {    // 13 in-rows feed 5 vertical outputs
            float4a v0 = *(const float4a*)(sp + rr * WIN);
            float4a v1 = *(const float4a*)(sp + rr * WIN + 4);
            float xv[8] = {v0.x, v0.y, v0.z, v0.w, v1.x, v1.y, v1.z, v1.w};
#pragma unroll
            for (int t = 0; t < 5; ++t) {
                const int kh = rr - STRIDE * t;
                if (kh >= 0 && kh < KSZ) {
#pragma unroll
                    for (int kw = 0; kw < KSZ; ++kw) {
                        const float w = wr[kh * KSZ + kw];
                        acc[t][0] = fmaf(xv[kw],     w, acc[t][0]);
                        acc[t][1] = fmaf(xv[kw + 2], w, acc[t][1]);
                    }
                }
            }
        }
    }

    float* op = out + (size_t)bc * (HO * WO) + (size_t)(ho0 + 5 * ty) * WO + 2 * px;
#pragma unroll
    for (int t = 0; t < 5; ++t) {
        float2a v = {acc[t][0], acc[t][1]};
        *(float2a*)(op + (size_t)t * WO) = v;   // 8B aligned, coalesced
    }
}

extern "C" void kernel_launch(void* const* d_in, const int* in_sizes, int n_in,
                              void* d_out, int out_size, void* d_ws, size_t ws_size,
                              hipStream_t stream)
{
    const float* x  = (const float*)d_in[0];
    const float* Wt = (const float*)d_in[1];
    float* out = (float*)d_out;

    conv5_lds_kernel<<<dim3(NWG), dim3(TPB), 0, stream>>>(x, Wt, out);
}

// Round 5
// 72.434 us; speedup vs baseline: 1.1600x; 1.0249x over previous
//
#include <hip/hip_runtime.h>

#define BATCH 8
#define CH 64
#define CIN 3
#define HIN 224
#define WIN 224
#define KSZ 5
#define STRIDE 2
#define HO 110
#define WO 110
#define HW (HIN * WIN)

#define TROWS 10                      // output rows per tile
#define TILES (HO / TROWS)            // 11
#define NPLANES (BATCH * CH)          // 512 persistent blocks, 1 plane each
#define INROWS (STRIDE * (TROWS - 1) + KSZ)  // 23 input rows per tile
#define SLABF (INROWS * WIN)          // 5152 floats per ci-slab
#define SLABU (SLABF / 4)             // 1288 16B units (exact)
#define TPB 128
#define NITER_S 11                    // ceil(1288/128) -> 11 full-exec DMA/wave
#define PADU (NITER_S * TPB)          // 1408 units (pad tail clamped)
#define NSLAB (TILES * CIN)           // 33 slab-stages per block

typedef float float4a __attribute__((ext_vector_type(4)));
typedef float float2a __attribute__((ext_vector_type(2)));

__device__ __forceinline__ void gload16(const float* src, float* ldsdst) {
    __builtin_amdgcn_global_load_lds(
        (const __attribute__((address_space(1))) void*)src,
        (__attribute__((address_space(3))) void*)ldsdst, 16, 0, 0);
}

// issue exactly NITER_S full-exec DMA instrs (per wave) for slab sl -> xbuf
__device__ __forceinline__ void stage_slab(const float* gplane, float* xbuf,
                                           int sl, int tid) {
    const int tile = sl / CIN;
    const int ci = sl - CIN * tile;
    const float* src0 = gplane + (size_t)ci * HW + (size_t)(tile * TROWS * STRIDE) * WIN;
#pragma unroll
    for (int k = 0; k < NITER_S; ++k) {
        const int u = k * TPB + tid;
        const int uc = (u < SLABU) ? u : (SLABU - 1);     // clamp: keep all lanes active
        // LDS dest: wave-uniform base + lane*16 (HW adds lane offset)
        gload16(src0 + (size_t)uc * 4, xbuf + (size_t)(k * TPB + (tid & ~63)) * 4);
    }
}

__global__ __launch_bounds__(TPB) void conv5_pipe_kernel(
    const float* __restrict__ x,
    const float* __restrict__ Wt,
    float* __restrict__ out)
{
    __shared__ float xs[2][PADU * 4];        // 2 x 22528 B double buffer
    __shared__ float wsh[CIN * KSZ * KSZ];   // 75 weights, loaded once

    const int bc = blockIdx.x;               // one (b,c) plane per block
    const int c = bc & (CH - 1);
    const int tid = threadIdx.x;
    const float* gplane = x + (size_t)bc * (CIN * HW);

    if (tid < CIN * KSZ * KSZ) wsh[tid] = Wt[c * (CIN * KSZ * KSZ) + tid];
    __syncthreads();                         // prologue-only full drain (weights)

    stage_slab(gplane, xs[0], 0, tid);       // prime the pipeline: 2 slabs in flight
    stage_slab(gplane, xs[1], 1, tid);

    const int px = tid % 55;                 // cols 2px, 2px+1   (valid if tid<110)
    const int ty = tid / 55;                 // rows +5*ty .. +5*ty+4

    float acc[5][2];
#pragma unroll
    for (int t = 0; t < 5; ++t) { acc[t][0] = 0.f; acc[t][1] = 0.f; }

    for (int s = 0; s < NSLAB; ++s) {
        // wait for slab s's 11 DMAs (leave slab s+1's 11 in flight), then sync
        if (s < NSLAB - 1) {
            asm volatile("s_waitcnt vmcnt(11) lgkmcnt(0)" ::: "memory");
        } else {
            asm volatile("s_waitcnt vmcnt(0) lgkmcnt(0)" ::: "memory");
        }
        __builtin_amdgcn_s_barrier();
        __builtin_amdgcn_sched_barrier(0);

        const int tile = s / CIN;
        const int ci = s - CIN * tile;

        if (tid < 110) {
            const float* wp = wsh + ci * (KSZ * KSZ);
            float wr[KSZ * KSZ];
#pragma unroll
            for (int i = 0; i < KSZ * KSZ; ++i) wr[i] = wp[i];

            const float* sp = xs[s & 1] + ty * (TROWS * WIN) + 4 * px;
#pragma unroll
            for (int rr = 0; rr < 13; ++rr) {
                float4a v0 = *(const float4a*)(sp + rr * WIN);
                float4a v1 = *(const float4a*)(sp + rr * WIN + 4);
                float xv[8] = {v0.x, v0.y, v0.z, v0.w, v1.x, v1.y, v1.z, v1.w};
#pragma unroll
                for (int t = 0; t < 5; ++t) {
                    const int kh = rr - STRIDE * t;
                    if (kh >= 0 && kh < KSZ) {
#pragma unroll
                        for (int kw = 0; kw < KSZ; ++kw) {
                            const float w = wr[kh * KSZ + kw];
                            acc[t][0] = fmaf(xv[kw],     w, acc[t][0]);
                            acc[t][1] = fmaf(xv[kw + 2], w, acc[t][1]);
                        }
                    }
                }
            }

            if (ci == CIN - 1) {             // tile finished: write 5x2 and reset
                float* op = out + (size_t)bc * (HO * WO)
                                + (size_t)(tile * TROWS + 5 * ty) * WO + 2 * px;
#pragma unroll
                for (int t = 0; t < 5; ++t) {
                    float2a v = {acc[t][0], acc[t][1]};
                    *(float2a*)(op + (size_t)t * WO) = v;
                    acc[t][0] = 0.f; acc[t][1] = 0.f;
                }
            }
        }

        // readers done (lgkm drained), then let DMA overwrite this buffer
        asm volatile("s_waitcnt lgkmcnt(0)" ::: "memory");
        __builtin_amdgcn_s_barrier();
        __builtin_amdgcn_sched_barrier(0);

        if (s + 2 < NSLAB) stage_slab(gplane, xs[s & 1], s + 2, tid);
    }
}

extern "C" void kernel_launch(void* const* d_in, const int* in_sizes, int n_in,
                              void* d_out, int out_size, void* d_ws, size_t ws_size,
                              hipStream_t stream)
{
    const float* x  = (const float*)d_in[0];
    const float* Wt = (const float*)d_in[1];
    float* out = (float*)d_out;

    conv5_pipe_kernel<<<dim3(NPLANES), dim3(TPB), 0, stream>>>(x, Wt, out);
}

// Round 6
// 70.835 us; speedup vs baseline: 1.1862x; 1.0226x over previous
//
#include <hip/hip_runtime.h>

#define BATCH 8
#define CH 64
#define CIN 3
#define HIN 224
#define WIN 224
#define KSZ 5
#define STRIDE 2
#define HO 110
#define WO 110
#define HW (HIN * WIN)

#define TPB 128
#define RING 12                       // LDS ring: 12 input rows per ci
#define HALF_OUT 55                   // output rows per block (half plane)
#define NWG (BATCH * CH * 2)          // 1024 = 8*128 -> bijective XCD swizzle
#define LAST_IN 112                   // last block-local input row (113 rows: 0..112)
#define NW 75                         // weights per channel group

typedef float float2a __attribute__((ext_vector_type(2)));

__device__ __forceinline__ void gload16(const float* src, float* ldsdst) {
    __builtin_amdgcn_global_load_lds(
        (const __attribute__((address_space(1))) void*)src,
        (__attribute__((address_space(3))) void*)ldsdst, 16, 0, 0);
}

__global__ __launch_bounds__(TPB) void conv5_ring_kernel(
    const float* __restrict__ x,
    const float* __restrict__ Wt,
    float* __restrict__ out)
{
    __shared__ float xs[CIN][RING][WIN];    // 32,256 B ring
    __shared__ float wsh[NW];               // 300 B

    // bijective XCD swizzle; both halves of a plane land on one XCD
    const int wg  = blockIdx.x;
    const int swz = (wg & 7) * (NWG >> 3) + (wg >> 3);
    const int bc   = swz >> 1;
    const int half = swz & 1;
    const int c = bc & (CH - 1);
    const int tid = threadIdx.x;
    const int lane = tid & 63;
    const int wid  = tid >> 6;

    // block-local input origin: row 110*half of the plane (rows +0..112 valid)
    const float* gplane = x + (size_t)bc * (CIN * HW) + (size_t)(half * 110) * WIN;

    if (tid < NW) wsh[tid] = Wt[c * NW + tid];
    __syncthreads();
    float wr[NW];
#pragma unroll
    for (int i = 0; i < NW; ++i) wr[i] = wsh[i];   // broadcast reads

    // ---- prologue: stage rows 0..9 (wave parity split: 15 DMA instrs/wave) ----
#pragma unroll
    for (int r = 0; r < 10; ++r) {
        if ((r & 1) == wid) {
#pragma unroll
            for (int ci = 0; ci < CIN; ++ci) {
                const float* src = gplane + (size_t)ci * HW + (size_t)r * WIN + lane * 4;
                if (lane < 56) gload16(src, &xs[ci][r][0]);   // 56 lanes x 16B = 896B row
            }
        }
    }

    const int p = tid;   // output column (if < 110)
    float* orow = out + (size_t)bc * (HO * WO) + (size_t)(half * HALF_OUT) * WO + p;

    for (int j = 0; j < HALF_OUT; ++j) {
        // ---- stage(j): rows 2j+10 (wave0) / 2j+11 (wave1) into slots of rows
        //      2j-2 / 2j-1 (dead since step j-1's trailing barrier). 3 instr/wave.
        {
            const int virt = 2 * j + 10 + wid;
            const int rsrc = virt > LAST_IN ? LAST_IN : virt;   // tail clamp (dead slots)
            const int slot = virt % RING;
#pragma unroll
            for (int ci = 0; ci < CIN; ++ci) {
                const float* src = gplane + (size_t)ci * HW + (size_t)rsrc * WIN + lane * 4;
                if (lane < 56) gload16(src, &xs[ci][slot][0]);
            }
        }

        // wait: everything older than the newest 9 VMEM ops (= stages j-2,j-1,j,
        // modulo interleaved stores which only make this more conservative)
        asm volatile("s_waitcnt vmcnt(9)" ::: "memory");
        __builtin_amdgcn_sched_barrier(0);
        __builtin_amdgcn_s_barrier();
        __builtin_amdgcn_sched_barrier(0);

        // ---- compute output row j from ring rows 2j..2j+4 ----
        if (p < WO) {
            const int s0 = (2 * j) % RING;
            float a = 0.f;
#pragma unroll
            for (int ci = 0; ci < CIN; ++ci) {
#pragma unroll
                for (int kh = 0; kh < KSZ; ++kh) {
                    int sk = s0 + kh; if (sk >= RING) sk -= RING;
                    const float* rp = &xs[ci][sk][2 * p];
                    float2a v01 = *(const float2a*)rp;         // 8B aligned
                    float2a v23 = *(const float2a*)(rp + 2);
                    float   v4  = rp[4];
                    const float* w = wr + ci * 25 + kh * 5;    // static reg indices
                    a = fmaf(v01.x, w[0], a);
                    a = fmaf(v01.y, w[1], a);
                    a = fmaf(v23.x, w[2], a);
                    a = fmaf(v23.y, w[3], a);
                    a = fmaf(v4,    w[4], a);
                }
            }
            orow[(size_t)j * WO] = a;   // 110 contiguous floats per row
        }

        // readers' LDS loads complete before any wave can start overwriting slots
        asm volatile("s_waitcnt lgkmcnt(0)" ::: "memory");
        __builtin_amdgcn_sched_barrier(0);
        __builtin_amdgcn_s_barrier();
        __builtin_amdgcn_sched_barrier(0);
    }

    // drain DMA before LDS is deallocated/reassigned
    asm volatile("s_waitcnt vmcnt(0)" ::: "memory");
}

extern "C" void kernel_launch(void* const* d_in, const int* in_sizes, int n_in,
                              void* d_out, int out_size, void* d_ws, size_t ws_size,
                              hipStream_t stream)
{
    const float* x  = (const float*)d_in[0];
    const float* Wt = (const float*)d_in[1];
    float* out = (float*)d_out;

    conv5_ring_kernel<<<dim3(NWG), dim3(TPB), 0, stream>>>(x, Wt, out);
}